// Round 1
// baseline (571.299 us; speedup 1.0000x reference)
//
#include <hip/hip_runtime.h>

#define N_NODES_C 1000
#define N_EDGES_C 8000
#define BATCH_C   64
#define IN_DIM_C  64
#define HID_C     128
#define NT (BATCH_C * N_NODES_C)   // 64000 total nodes
#define ET (BATCH_C * N_EDGES_C)   // 512000 total edges

// workspace layout (float offsets)
#define WS_DEG   0                  // 64000 floats: deg -> dinv (in place)
#define WS_EWS   64000              // 8000 floats: sparsified edge weights
#define WS_GRAW  72000              // 2048 floats: g accumulator (64 x 32)
#define WS_NORM  74048              // 512000 floats: per-edge norm
#define WS_H2    586240             // 8192000 floats: h2 -> relu_h (in place)
// total: 8,778,240 floats = 35.1 MB

// ---------------------------------------------------------------- prep ----
// ew sparsify + ni clamp (both are outputs), deg := 1 (self loop), g := 0
__global__ __launch_bounds__(256) void prep(const float* __restrict__ ew_in,
                                            const float* __restrict__ ni,
                                            float* __restrict__ ws,
                                            float* __restrict__ out) {
    int i = blockIdx.x * 256 + threadIdx.x;       // grid covers 64000
    if (i < NT) ws[WS_DEG + i] = 1.0f;
    if (i < N_EDGES_C) {
        float w = ew_in[i];
        float s = (w < 0.2f) ? 0.0f : fminf(w, 1.0f);
        ws[WS_EWS + i] = s;
        out[128 + i] = s;                         // output 1: ew
    }
    if (i < N_NODES_C) {
        float v = ni[i];
        out[128 + N_EDGES_C + i] = fminf(fmaxf(v, 0.0f), 1.0f);  // output 2
    }
    if (i < BATCH_C * 32) ws[WS_GRAW + i] = 0.0f;
}

// ---------------------------------------------------------------- degree --
__global__ __launch_bounds__(256) void deg_accum(const int* __restrict__ ei,
                                                 const float* __restrict__ ews,
                                                 float* __restrict__ deg) {
    int e = blockIdx.x * 256 + threadIdx.x;       // < ET
    int d = ei[ET + e];                           // dst
    atomicAdd(&deg[d], ews[e % N_EDGES_C]);
}

__global__ __launch_bounds__(256) void to_dinv(float* __restrict__ deg) {
    int i = blockIdx.x * 256 + threadIdx.x;       // < NT
    deg[i] = rsqrtf(deg[i]);                      // deg >= 1 always (self loop)
}

// ------------------------------------------------------------- edge norm --
__global__ __launch_bounds__(256) void edge_norm(const int* __restrict__ ei,
                                                 float* __restrict__ ws) {
    int e = blockIdx.x * 256 + threadIdx.x;       // < ET
    int s = ei[e];
    int d = ei[ET + e];
    const float* dinv = ws + WS_DEG;
    ws[WS_NORM + e] = dinv[s] * ws[WS_EWS + e % N_EDGES_C] * dinv[d];
}

// ------------------------------------------------------- h2 = (x*ni) @ W1 -
// 128-row x 128-col block tile, K=64. 256 threads, 8x8 micro-tile/thread.
__global__ __launch_bounds__(256) void gemm_h2(const float* __restrict__ x,
                                               const float* __restrict__ ni,
                                               const float* __restrict__ W1,
                                               float* __restrict__ h2) {
    __shared__ float xs[128][65];      // +1 pad: conflict-free scalar reads
    __shared__ float wsm[64 * 128];    // W1 staged linear
    int tid = threadIdx.x;
    int base = blockIdx.x * 128;       // row base (500 blocks cover 64000)

    // stage x tile scaled by raw node_importance (tile rows are contiguous)
    #pragma unroll
    for (int i = 0; i < 8; ++i) {
        int idx = i * 1024 + tid * 4;              // 8192 floats
        int r = idx >> 6, d = idx & 63;
        float4 v = *(const float4*)&x[(base + r) * 64 + d];
        float s = ni[(base + r) % N_NODES_C];
        xs[r][d + 0] = v.x * s;
        xs[r][d + 1] = v.y * s;
        xs[r][d + 2] = v.z * s;
        xs[r][d + 3] = v.w * s;
    }
    // stage W1 (linear 8192 floats)
    #pragma unroll
    for (int i = 0; i < 8; ++i) {
        int idx = i * 1024 + tid * 4;
        *(float4*)&wsm[idx] = *(const float4*)&W1[idx];
    }
    __syncthreads();

    int tx = tid & 15, ty = tid >> 4;
    int r0 = ty * 8, c0 = tx * 8;
    float acc[8][8];
    #pragma unroll
    for (int i = 0; i < 8; ++i)
        #pragma unroll
        for (int j = 0; j < 8; ++j) acc[i][j] = 0.0f;

    for (int d = 0; d < 64; ++d) {
        float a[8];
        #pragma unroll
        for (int i = 0; i < 8; ++i) a[i] = xs[r0 + i][d];
        float4 b0 = *(float4*)&wsm[d * 128 + c0];
        float4 b1 = *(float4*)&wsm[d * 128 + c0 + 4];
        float b[8] = {b0.x, b0.y, b0.z, b0.w, b1.x, b1.y, b1.z, b1.w};
        #pragma unroll
        for (int i = 0; i < 8; ++i)
            #pragma unroll
            for (int j = 0; j < 8; ++j)
                acc[i][j] = fmaf(a[i], b[j], acc[i][j]);
    }

    #pragma unroll
    for (int i = 0; i < 8; ++i) {
        float* dst = &h2[(base + r0 + i) * HID_C + c0];
        float4 o0 = {acc[i][0], acc[i][1], acc[i][2], acc[i][3]};
        float4 o1 = {acc[i][4], acc[i][5], acc[i][6], acc[i][7]};
        *(float4*)dst = o0;
        *(float4*)(dst + 4) = o1;
    }
}

// --------------------------------------------------- edge aggregation -----
// One block per (graph, 16-feature chunk): LDS acc[1000][16] = 62.5 KB.
// Self-loop + bias + relu fused into writeout, IN PLACE over h2
// (block owns disjoint (graph rows, column chunk); reads precede barrier).
__global__ __launch_bounds__(256) void aggregate(const int* __restrict__ ei,
                                                 const float* __restrict__ ws,
                                                 float* __restrict__ h2,
                                                 const float* __restrict__ b1) {
    __shared__ float acc[N_NODES_C * 16];          // 64000 B
    int g  = blockIdx.x >> 3;
    int c0 = (blockIdx.x & 7) * 16;
    int tid = threadIdx.x;

    for (int i = tid; i < N_NODES_C * 16 / 4; i += 256)
        ((float4*)acc)[i] = make_float4(0.f, 0.f, 0.f, 0.f);
    __syncthreads();

    const float* norm = ws + WS_NORM;
    const float* dinv = ws + WS_DEG;
    int f = tid & 15, slot = tid >> 4;             // 16 slots x 16 feats
    int ebase = g * N_EDGES_C;
    int gbase = g * N_NODES_C;

    #pragma unroll 4
    for (int it = 0; it < N_EDGES_C / 16; ++it) {  // 500 iters, 16 edges each
        int e  = ebase + it * 16 + slot;
        int s  = ei[e];                            // broadcast within slot
        int dl = ei[ET + e] - gbase;               // local dst
        float nm = norm[e];
        float v  = h2[s * HID_C + c0 + f];         // 64B coalesced per slot
        atomicAdd(&acc[dl * 16 + f], v * nm);      // ds_add_f32, ~2 lanes/bank
    }
    __syncthreads();

    float bv = b1[c0 + f];                         // idx&15 == f below
    for (int idx = tid; idx < N_NODES_C * 16; idx += 256) {
        int v = idx >> 4;
        int node = gbase + v;
        float dv = dinv[node];
        float val = acc[idx] + h2[node * HID_C + c0 + f] * (dv * dv) + bv;
        h2[node * HID_C + c0 + f] = fmaxf(val, 0.0f);   // relu_h in place
    }
}

// ------------------------------------------- g = rh[64x128000] @ Wn + bn --
// 256 blocks over k-chunks of 500; thread (j = tid&31, bg = tid>>5) owns
// 8 graphs; Wn and rh each read exactly once; fp32 atomics into g_raw.
__global__ __launch_bounds__(256) void reduce_g(const float* __restrict__ rh,
                                                const float* __restrict__ Wn,
                                                float* __restrict__ g_raw) {
    int tid = threadIdx.x;
    int j = tid & 31, bg = tid >> 5;
    int k0 = blockIdx.x * 500;
    float acc[8] = {0, 0, 0, 0, 0, 0, 0, 0};
    for (int kk = 0; kk < 500; ++kk) {
        int k = k0 + kk;
        float w = Wn[k * 32 + j];                  // coalesced 128B
        #pragma unroll
        for (int u = 0; u < 8; ++u)
            acc[u] = fmaf(rh[(bg * 8 + u) * 128000 + k], w, acc[u]);
    }
    #pragma unroll
    for (int u = 0; u < 8; ++u)
        atomicAdd(&g_raw[(bg * 8 + u) * 32 + j], acc[u]);
}

// ------------------------------------------------ out = (g+bn) @ Wc + bc --
__global__ void final_out(const float* __restrict__ ws,
                          const float* __restrict__ bn,
                          const float* __restrict__ Wc,
                          const float* __restrict__ bc,
                          float* __restrict__ out) {
    int b = threadIdx.x;
    if (b >= BATCH_C) return;
    const float* g_raw = ws + WS_GRAW;
    float o0 = bc[0], o1 = bc[1];
    #pragma unroll
    for (int jj = 0; jj < 32; ++jj) {
        float gv = g_raw[b * 32 + jj] + bn[jj];
        o0 = fmaf(gv, Wc[jj * 2 + 0], o0);
        o1 = fmaf(gv, Wc[jj * 2 + 1], o1);
    }
    out[b * 2 + 0] = o0;
    out[b * 2 + 1] = o1;
}

// --------------------------------------------------------------------------
extern "C" void kernel_launch(void* const* d_in, const int* in_sizes, int n_in,
                              void* d_out, int out_size, void* d_ws, size_t ws_size,
                              hipStream_t stream) {
    const float* x  = (const float*)d_in[0];
    const int*   ei = (const int*)d_in[1];
    // d_in[2] = batch (unused: graphs are contiguous blocks of 1000 nodes)
    const float* ew = (const float*)d_in[3];
    const float* ni = (const float*)d_in[4];
    const float* W1 = (const float*)d_in[5];
    const float* b1 = (const float*)d_in[6];
    const float* Wn = (const float*)d_in[7];
    const float* bn = (const float*)d_in[8];
    const float* Wc = (const float*)d_in[9];
    const float* bc = (const float*)d_in[10];
    float* out = (float*)d_out;
    float* ws  = (float*)d_ws;

    prep<<<NT / 256, 256, 0, stream>>>(ew, ni, ws, out);
    deg_accum<<<ET / 256, 256, 0, stream>>>(ei, ws + WS_EWS, ws + WS_DEG);
    to_dinv<<<NT / 256, 256, 0, stream>>>(ws + WS_DEG);
    gemm_h2<<<NT / 128, 256, 0, stream>>>(x, ni, W1, ws + WS_H2);
    edge_norm<<<ET / 256, 256, 0, stream>>>(ei, ws);
    aggregate<<<BATCH_C * 8, 256, 0, stream>>>(ei, ws, ws + WS_H2, b1);
    reduce_g<<<256, 256, 0, stream>>>(ws + WS_H2, Wn, ws + WS_GRAW);
    final_out<<<1, 64, 0, stream>>>(ws, bn, Wc, bc, out);
}

// Round 2
// 545.571 us; speedup vs baseline: 1.0472x; 1.0472x over previous
//
#include <hip/hip_runtime.h>

#define N_NODES_C 1000
#define N_EDGES_C 8000
#define BATCH_C   64
#define IN_DIM_C  64
#define HID_C     128
#define NT (BATCH_C * N_NODES_C)   // 64000 total nodes
#define ET (BATCH_C * N_EDGES_C)   // 512000 total edges

// workspace layout (float offsets)
#define WS_DEG   0                  // 64000 floats: dinv
#define WS_EWS   64000              // 8000 floats: sparsified edge weights
#define WS_GRAW  72000              // 2048 floats: g accumulator (64 x 32)
#define WS_H2    586240             // 8192000 floats: h2 -> relu_h (in place)

// ---------------------------------------------------------------- prep ----
// ew sparsify + ni clamp (both are outputs), g := 0
__global__ __launch_bounds__(256) void prep(const float* __restrict__ ew_in,
                                            const float* __restrict__ ni,
                                            float* __restrict__ ws,
                                            float* __restrict__ out) {
    int i = blockIdx.x * 256 + threadIdx.x;       // grid covers 8192
    if (i < N_EDGES_C) {
        float w = ew_in[i];
        float s = (w < 0.2f) ? 0.0f : fminf(w, 1.0f);
        ws[WS_EWS + i] = s;
        out[128 + i] = s;                         // output 1: ew
    }
    if (i < N_NODES_C) {
        float v = ni[i];
        out[128 + N_EDGES_C + i] = fminf(fmaxf(v, 0.0f), 1.0f);  // output 2
    }
    if (i < BATCH_C * 32) ws[WS_GRAW + i] = 0.0f;
}

// ------------------------------------------------------- degree -> dinv ---
// One block per graph: LDS degree accumulation (self-loop=1), write rsqrt.
__global__ __launch_bounds__(256) void deg_dinv(const int* __restrict__ ei,
                                                float* __restrict__ ws) {
    __shared__ float dacc[N_NODES_C];
    int g = blockIdx.x, tid = threadIdx.x;
    for (int i = tid; i < N_NODES_C; i += 256) dacc[i] = 1.0f;   // self loop
    __syncthreads();
    int ebase = g * N_EDGES_C, gbase = g * N_NODES_C;
    for (int le = tid; le < N_EDGES_C; le += 256) {
        int d = ei[ET + ebase + le];              // global dst id
        atomicAdd(&dacc[d - gbase], ws[WS_EWS + le]);
    }
    __syncthreads();
    for (int i = tid; i < N_NODES_C; i += 256)
        ws[WS_DEG + gbase + i] = rsqrtf(dacc[i]); // deg >= 1 always
}

// ------------------------------------------------------- h2 = (x*ni) @ W1 -
// 128-row x 128-col block tile, K=64. 256 threads, 8x8 micro-tile/thread.
__global__ __launch_bounds__(256) void gemm_h2(const float* __restrict__ x,
                                               const float* __restrict__ ni,
                                               const float* __restrict__ W1,
                                               float* __restrict__ h2) {
    __shared__ float xs[128][65];
    __shared__ float wsm[64 * 128];
    int tid = threadIdx.x;
    int base = blockIdx.x * 128;

    #pragma unroll
    for (int i = 0; i < 8; ++i) {
        int idx = i * 1024 + tid * 4;
        int r = idx >> 6, d = idx & 63;
        float4 v = *(const float4*)&x[(base + r) * 64 + d];
        float s = ni[(base + r) % N_NODES_C];
        xs[r][d + 0] = v.x * s;
        xs[r][d + 1] = v.y * s;
        xs[r][d + 2] = v.z * s;
        xs[r][d + 3] = v.w * s;
    }
    #pragma unroll
    for (int i = 0; i < 8; ++i) {
        int idx = i * 1024 + tid * 4;
        *(float4*)&wsm[idx] = *(const float4*)&W1[idx];
    }
    __syncthreads();

    int tx = tid & 15, ty = tid >> 4;
    int r0 = ty * 8, c0 = tx * 8;
    float acc[8][8];
    #pragma unroll
    for (int i = 0; i < 8; ++i)
        #pragma unroll
        for (int j = 0; j < 8; ++j) acc[i][j] = 0.0f;

    for (int d = 0; d < 64; ++d) {
        float a[8];
        #pragma unroll
        for (int i = 0; i < 8; ++i) a[i] = xs[r0 + i][d];
        float4 b0 = *(float4*)&wsm[d * 128 + c0];
        float4 b1 = *(float4*)&wsm[d * 128 + c0 + 4];
        float b[8] = {b0.x, b0.y, b0.z, b0.w, b1.x, b1.y, b1.z, b1.w};
        #pragma unroll
        for (int i = 0; i < 8; ++i)
            #pragma unroll
            for (int j = 0; j < 8; ++j)
                acc[i][j] = fmaf(a[i], b[j], acc[i][j]);
    }

    #pragma unroll
    for (int i = 0; i < 8; ++i) {
        float* dst = &h2[(base + r0 + i) * HID_C + c0];
        float4 o0 = {acc[i][0], acc[i][1], acc[i][2], acc[i][3]};
        float4 o1 = {acc[i][4], acc[i][5], acc[i][6], acc[i][7]};
        *(float4*)dst = o0;
        *(float4*)(dst + 4) = o1;
    }
}

// --------------------------------------------------- edge aggregation -----
// 1024 blocks: bid = chunk*64 + graph  =>  bid%8 == graph%8, so all 16
// chunk-blocks of a graph land on the SAME XCD (round-robin dispatch) and
// the graph's 512KB h2 slice stays L2-resident. 8-feature chunks: 32KB LDS
// -> 5 blocks/CU (20 waves) for latency hiding. norm computed inline from
// dinv gathers (4KB slice, L1-hit). Self-loop + bias + relu fused into the
// in-place writeout (block owns disjoint rowsxcols; reads precede barrier).
__global__ __launch_bounds__(256) void aggregate(const int* __restrict__ ei,
                                                 const float* __restrict__ ws,
                                                 float* __restrict__ h2,
                                                 const float* __restrict__ b1) {
    __shared__ float acc[N_NODES_C * 8];           // 32000 B
    int bid = blockIdx.x;
    int g  = bid & 63;
    int c0 = (bid >> 6) * 8;
    int tid = threadIdx.x;

    for (int i = tid; i < N_NODES_C * 8 / 4; i += 256)
        ((float4*)acc)[i] = make_float4(0.f, 0.f, 0.f, 0.f);
    __syncthreads();

    const float* dinv = ws + WS_DEG;
    const float* ews  = ws + WS_EWS;
    int f = tid & 7, slot = tid >> 3;              // 32 edge slots x 8 feats
    int ebase = g * N_EDGES_C;
    int gbase = g * N_NODES_C;

    // 50 groups x 5 edges/thread: 5 independent gathers in flight per lane
    for (int grp = 0; grp < 50; ++grp) {
        int sg[5], dg[5];
        float w[5];
        #pragma unroll
        for (int u = 0; u < 5; ++u) {
            int le = (grp * 5 + u) * 32 + slot;
            sg[u] = ei[ebase + le];                // global src id
            dg[u] = ei[ET + ebase + le];           // global dst id
            w[u]  = ews[le];
        }
        float dvs[5], dvd[5], hv[5];
        #pragma unroll
        for (int u = 0; u < 5; ++u) {
            dvs[u] = dinv[sg[u]];                  // L1-resident 4KB slice
            dvd[u] = dinv[dg[u]];
            hv[u]  = h2[sg[u] * HID_C + c0 + f];   // 32B coalesced, L2-hit
        }
        #pragma unroll
        for (int u = 0; u < 5; ++u)
            atomicAdd(&acc[(dg[u] - gbase) * 8 + f],
                      hv[u] * (dvs[u] * w[u] * dvd[u]));
    }
    __syncthreads();

    for (int idx = tid; idx < N_NODES_C * 8; idx += 256) {
        int v = idx >> 3, ff = idx & 7;
        int node = gbase + v;
        float dv = dinv[node];
        float val = acc[idx] + h2[node * HID_C + c0 + ff] * (dv * dv) + b1[c0 + ff];
        h2[node * HID_C + c0 + ff] = fmaxf(val, 0.0f);   // relu_h in place
    }
}

// ------------------------------------------- g = rh[64x128000] @ Wn + bn --
__global__ __launch_bounds__(256) void reduce_g(const float* __restrict__ rh,
                                                const float* __restrict__ Wn,
                                                float* __restrict__ g_raw) {
    int tid = threadIdx.x;
    int j = tid & 31, bg = tid >> 5;
    int k0 = blockIdx.x * 500;
    float acc[8] = {0, 0, 0, 0, 0, 0, 0, 0};
    for (int kk = 0; kk < 500; ++kk) {
        int k = k0 + kk;
        float w = Wn[k * 32 + j];                  // coalesced 128B
        #pragma unroll
        for (int u = 0; u < 8; ++u)
            acc[u] = fmaf(rh[(bg * 8 + u) * 128000 + k], w, acc[u]);
    }
    #pragma unroll
    for (int u = 0; u < 8; ++u)
        atomicAdd(&g_raw[(bg * 8 + u) * 32 + j], acc[u]);
}

// ------------------------------------------------ out = (g+bn) @ Wc + bc --
__global__ void final_out(const float* __restrict__ ws,
                          const float* __restrict__ bn,
                          const float* __restrict__ Wc,
                          const float* __restrict__ bc,
                          float* __restrict__ out) {
    int b = threadIdx.x;
    if (b >= BATCH_C) return;
    const float* g_raw = ws + WS_GRAW;
    float o0 = bc[0], o1 = bc[1];
    #pragma unroll
    for (int jj = 0; jj < 32; ++jj) {
        float gv = g_raw[b * 32 + jj] + bn[jj];
        o0 = fmaf(gv, Wc[jj * 2 + 0], o0);
        o1 = fmaf(gv, Wc[jj * 2 + 1], o1);
    }
    out[b * 2 + 0] = o0;
    out[b * 2 + 1] = o1;
}

// --------------------------------------------------------------------------
extern "C" void kernel_launch(void* const* d_in, const int* in_sizes, int n_in,
                              void* d_out, int out_size, void* d_ws, size_t ws_size,
                              hipStream_t stream) {
    const float* x  = (const float*)d_in[0];
    const int*   ei = (const int*)d_in[1];
    // d_in[2] = batch (unused: graphs are contiguous blocks of 1000 nodes)
    const float* ew = (const float*)d_in[3];
    const float* ni = (const float*)d_in[4];
    const float* W1 = (const float*)d_in[5];
    const float* b1 = (const float*)d_in[6];
    const float* Wn = (const float*)d_in[7];
    const float* bn = (const float*)d_in[8];
    const float* Wc = (const float*)d_in[9];
    const float* bc = (const float*)d_in[10];
    float* out = (float*)d_out;
    float* ws  = (float*)d_ws;

    prep<<<32, 256, 0, stream>>>(ew, ni, ws, out);
    gemm_h2<<<NT / 128, 256, 0, stream>>>(x, ni, W1, ws + WS_H2);
    deg_dinv<<<BATCH_C, 256, 0, stream>>>(ei, ws);
    aggregate<<<BATCH_C * 16, 256, 0, stream>>>(ei, ws, ws + WS_H2, b1);
    reduce_g<<<256, 256, 0, stream>>>(ws + WS_H2, Wn, ws + WS_GRAW);
    final_out<<<1, 64, 0, stream>>>(ws, bn, Wc, bc, out);
}

// Round 3
// 293.300 us; speedup vs baseline: 1.9478x; 1.8601x over previous
//
#include <hip/hip_runtime.h>

#define N_NODES_C 1000
#define N_EDGES_C 8000
#define BATCH_C   64
#define IN_DIM_C  64
#define HID_C     128
#define NT (BATCH_C * N_NODES_C)   // 64000 total nodes
#define ET (BATCH_C * N_EDGES_C)   // 512000 total edges

// workspace layout (float offsets)
#define WS_DEG    0                 // 64000 f: dinv
#define WS_EWS    64000             // 8000 f: sparsified edge weights
#define WS_ROWP   72000             // 64*1024 ints: CSR row starts (+[1000]=8000)
#define WS_PEDGE  137536            // 512000 int2: (src_global, norm) in CSR order
#define WS_PART   1161536           // 256*2048 f: reduce_g partials
#define WS_H2     1685824           // 8192000 f: h2 -> relu_h (in place)
// total 9,877,824 floats = 39.5 MB

// ---------------------------------------------------------------- prep ----
__global__ __launch_bounds__(256) void prep(const float* __restrict__ ew_in,
                                            const float* __restrict__ ni,
                                            float* __restrict__ ws,
                                            float* __restrict__ out) {
    int i = blockIdx.x * 256 + threadIdx.x;       // grid covers 8192
    if (i < N_EDGES_C) {
        float w = ew_in[i];
        float s = (w < 0.2f) ? 0.0f : fminf(w, 1.0f);
        ws[WS_EWS + i] = s;
        out[128 + i] = s;                         // output 1: ew
    }
    if (i < N_NODES_C) {
        float v = ni[i];
        out[128 + N_EDGES_C + i] = fminf(fmaxf(v, 0.0f), 1.0f);  // output 2
    }
}

// ------------------------------------------------- degree + CSR build -----
// One block per graph. Pass1: weighted deg (float) + count (int) via LDS
// atomics (16k/block, was 1M feat-atomics/graph before). Scan counts ->
// row starts. Pass2: scatter (src, norm) int2 into CSR order.
__global__ __launch_bounds__(256) void deg_csr(const int* __restrict__ ei,
                                               float* __restrict__ ws) {
    __shared__ float dacc[N_NODES_C];
    __shared__ int   cnt[N_NODES_C];
    __shared__ int   rs[N_NODES_C + 8];
    __shared__ int   wtot[4];
    int g = blockIdx.x, tid = threadIdx.x;
    int lane = tid & 63, wid = tid >> 6;
    int ebase = g * N_EDGES_C, gbase = g * N_NODES_C;
    const float* ews = ws + WS_EWS;

    for (int i = tid; i < N_NODES_C; i += 256) { dacc[i] = 1.0f; cnt[i] = 0; }
    __syncthreads();

    for (int le = tid; le < N_EDGES_C; le += 256) {
        int dl = ei[ET + ebase + le] - gbase;
        atomicAdd(&dacc[dl], ews[le]);
        atomicAdd(&cnt[dl], 1);
    }
    __syncthreads();

    // dinv in place + to global
    for (int i = tid; i < N_NODES_C; i += 256) {
        float d = rsqrtf(dacc[i]);                // deg >= 1 (self loop)
        dacc[i] = d;
        ws[WS_DEG + gbase + i] = d;
    }

    // exclusive scan of cnt[0..999] -> rs (chunk-of-4 per thread + shfl scan)
    int s0 = 0, s1 = 0, s2 = 0, s3 = 0, tsum = 0;
    if (tid < 250) {
        s0 = cnt[4 * tid]; s1 = cnt[4 * tid + 1];
        s2 = cnt[4 * tid + 2]; s3 = cnt[4 * tid + 3];
        tsum = s0 + s1 + s2 + s3;
    }
    int v = tsum;
    #pragma unroll
    for (int off = 1; off < 64; off <<= 1) {
        int n = __shfl_up(v, off, 64);
        if (lane >= off) v += n;
    }
    if (lane == 63) wtot[wid] = v;
    __syncthreads();
    int base = 0;
    for (int w = 0; w < wid; ++w) base += wtot[w];
    int excl = base + v - tsum;
    if (tid < 250) {
        rs[4 * tid]     = excl;
        rs[4 * tid + 1] = excl + s0;
        rs[4 * tid + 2] = excl + s0 + s1;
        rs[4 * tid + 3] = excl + s0 + s1 + s2;
    }
    if (tid == 255) rs[N_NODES_C] = N_EDGES_C;
    __syncthreads();

    // row_ptr to global; cursor := row start (reuse cnt)
    int* rowp = (int*)(ws + WS_ROWP);
    for (int i = tid; i <= N_NODES_C; i += 256) rowp[g * 1024 + i] = rs[i];
    for (int i = tid; i < N_NODES_C; i += 256) cnt[i] = rs[i];
    __syncthreads();

    // pass2: scatter (src, norm) into CSR slots
    int2* pedge = (int2*)(ws + WS_PEDGE);
    for (int le = tid; le < N_EDGES_C; le += 256) {
        int s  = ei[ebase + le];                  // global src
        int dl = ei[ET + ebase + le] - gbase;
        float nm = dacc[s - gbase] * ews[le] * dacc[dl];
        int pos = atomicAdd(&cnt[dl], 1);
        pedge[ebase + pos] = make_int2(s, __float_as_int(nm));
    }
}

// ------------------------------------------------------- h2 = (x*ni) @ W1 -
__global__ __launch_bounds__(256) void gemm_h2(const float* __restrict__ x,
                                               const float* __restrict__ ni,
                                               const float* __restrict__ W1,
                                               float* __restrict__ h2) {
    __shared__ float xs[128][65];
    __shared__ float wsm[64 * 128];
    int tid = threadIdx.x;
    int base = blockIdx.x * 128;

    #pragma unroll
    for (int i = 0; i < 8; ++i) {
        int idx = i * 1024 + tid * 4;
        int r = idx >> 6, d = idx & 63;
        float4 v = *(const float4*)&x[(base + r) * 64 + d];
        float s = ni[(base + r) % N_NODES_C];
        xs[r][d + 0] = v.x * s;
        xs[r][d + 1] = v.y * s;
        xs[r][d + 2] = v.z * s;
        xs[r][d + 3] = v.w * s;
    }
    #pragma unroll
    for (int i = 0; i < 8; ++i) {
        int idx = i * 1024 + tid * 4;
        *(float4*)&wsm[idx] = *(const float4*)&W1[idx];
    }
    __syncthreads();

    int tx = tid & 15, ty = tid >> 4;
    int r0 = ty * 8, c0 = tx * 8;
    float acc[8][8];
    #pragma unroll
    for (int i = 0; i < 8; ++i)
        #pragma unroll
        for (int j = 0; j < 8; ++j) acc[i][j] = 0.0f;

    for (int d = 0; d < 64; ++d) {
        float a[8];
        #pragma unroll
        for (int i = 0; i < 8; ++i) a[i] = xs[r0 + i][d];
        float4 b0 = *(float4*)&wsm[d * 128 + c0];
        float4 b1 = *(float4*)&wsm[d * 128 + c0 + 4];
        float b[8] = {b0.x, b0.y, b0.z, b0.w, b1.x, b1.y, b1.z, b1.w};
        #pragma unroll
        for (int i = 0; i < 8; ++i)
            #pragma unroll
            for (int j = 0; j < 8; ++j)
                acc[i][j] = fmaf(a[i], b[j], acc[i][j]);
    }

    #pragma unroll
    for (int i = 0; i < 8; ++i) {
        float* dst = &h2[(base + r0 + i) * HID_C + c0];
        float4 o0 = {acc[i][0], acc[i][1], acc[i][2], acc[i][3]};
        float4 o1 = {acc[i][4], acc[i][5], acc[i][6], acc[i][7]};
        *(float4*)dst = o0;
        *(float4*)(dst + 4) = o1;
    }
}

// ------------------------------------------------------ SpMM (dst-major) --
// block = (graph, 16-feat chunk); bid&63 = graph -> all chunk-blocks of a
// graph share an XCD (L2-resident h2 slice). Thread = (dst-slot, feat-quad):
// register accumulation over the CSR row -- ZERO atomics (was 65.5M ds_add).
// Results staged in LDS; self-loop + bias + relu written in place after the
// barrier (all h2 gathers precede all h2 writes; block owns disjoint cols).
__global__ __launch_bounds__(256) void spmm(const float* __restrict__ ws_ro,
                                            float* __restrict__ h2,
                                            const float* __restrict__ b1) {
    __shared__ float res[N_NODES_C * 16];          // 64000 B
    int bid = blockIdx.x;
    int g  = bid & 63;
    int c0 = (bid >> 6) * 16;
    int tid = threadIdx.x;
    int fq = tid & 3, dslot = tid >> 2;            // 64 dsts in flight

    const int*  rowp  = (const int*)(ws_ro + WS_ROWP) + g * 1024;
    const int2* pedge = (const int2*)(ws_ro + WS_PEDGE) + g * N_EDGES_C;
    const float* dinv = ws_ro + WS_DEG;
    int gbase = g * N_NODES_C;

    for (int iter = 0; iter < 16; ++iter) {
        int d = iter * 64 + dslot;
        if (d < N_NODES_C) {
            int e0 = rowp[d], e1 = rowp[d + 1];
            float4 a = make_float4(0.f, 0.f, 0.f, 0.f);
            for (int e = e0; e < e1; ++e) {
                int2 ed = pedge[e];
                float nm = __int_as_float(ed.y);
                float4 hv = *(const float4*)&h2[ed.x * HID_C + c0 + fq * 4];
                a.x = fmaf(hv.x, nm, a.x);
                a.y = fmaf(hv.y, nm, a.y);
                a.z = fmaf(hv.z, nm, a.z);
                a.w = fmaf(hv.w, nm, a.w);
            }
            *(float4*)&res[d * 16 + fq * 4] = a;
        }
    }
    __syncthreads();

    for (int idx = tid; idx < N_NODES_C * 16; idx += 256) {
        int v = idx >> 4, f = idx & 15;
        int node = gbase + v;
        float dv = dinv[node];
        float val = res[idx] + h2[node * HID_C + c0 + f] * (dv * dv) + b1[c0 + f];
        h2[node * HID_C + c0 + f] = fmaxf(val, 0.0f);
    }
}

// ------------------------------------------- g partials: rh @ Wn chunks ---
// 256 blocks over k-chunks of 500. float4 rh broadcasts (4x fewer loads),
// partials to ws (no global atomics).
__global__ __launch_bounds__(256) void reduce_g(const float* __restrict__ rh,
                                                const float* __restrict__ Wn,
                                                float* __restrict__ part) {
    int tid = threadIdx.x;
    int j = tid & 31, bg = tid >> 5;               // bg: 8 graphs each
    int k0 = blockIdx.x * 500;                     // 500 % 4 == 0
    float acc[8] = {0, 0, 0, 0, 0, 0, 0, 0};
    for (int kk = 0; kk < 500; kk += 4) {
        int k = k0 + kk;
        float w0 = Wn[(k + 0) * 32 + j];           // coalesced 128B each
        float w1 = Wn[(k + 1) * 32 + j];
        float w2 = Wn[(k + 2) * 32 + j];
        float w3 = Wn[(k + 3) * 32 + j];
        #pragma unroll
        for (int u = 0; u < 8; ++u) {
            float4 r = *(const float4*)&rh[(bg * 8 + u) * 128000 + k];
            acc[u] = fmaf(r.x, w0, acc[u]);
            acc[u] = fmaf(r.y, w1, acc[u]);
            acc[u] = fmaf(r.z, w2, acc[u]);
            acc[u] = fmaf(r.w, w3, acc[u]);
        }
    }
    #pragma unroll
    for (int u = 0; u < 8; ++u)
        part[blockIdx.x * 2048 + (bg * 8 + u) * 32 + j] = acc[u];
}

// ---------------------- final: sum partials, +bn, @Wc, +bc (shfl reduce) --
__global__ __launch_bounds__(256) void final_out(const float* __restrict__ ws_ro,
                                                 const float* __restrict__ bn,
                                                 const float* __restrict__ Wc,
                                                 const float* __restrict__ bc,
                                                 float* __restrict__ out) {
    int gid = blockIdx.x * 256 + threadIdx.x;      // 2048 = 64 graphs x 32 j
    int g = gid >> 5, j = gid & 31;
    const float* part = ws_ro + WS_PART;
    float s = 0.0f;
    for (int c = 0; c < 256; ++c)
        s += part[c * 2048 + gid];                 // coalesced across gid
    float gv = s + bn[j];
    float o0 = gv * Wc[j * 2 + 0];
    float o1 = gv * Wc[j * 2 + 1];
    #pragma unroll
    for (int off = 16; off >= 1; off >>= 1) {      // reduce within 32-group
        o0 += __shfl_xor(o0, off);
        o1 += __shfl_xor(o1, off);
    }
    if (j == 0) {
        out[g * 2 + 0] = o0 + bc[0];
        out[g * 2 + 1] = o1 + bc[1];
    }
}

// --------------------------------------------------------------------------
extern "C" void kernel_launch(void* const* d_in, const int* in_sizes, int n_in,
                              void* d_out, int out_size, void* d_ws, size_t ws_size,
                              hipStream_t stream) {
    const float* x  = (const float*)d_in[0];
    const int*   ei = (const int*)d_in[1];
    const float* ew = (const float*)d_in[3];
    const float* ni = (const float*)d_in[4];
    const float* W1 = (const float*)d_in[5];
    const float* b1 = (const float*)d_in[6];
    const float* Wn = (const float*)d_in[7];
    const float* bn = (const float*)d_in[8];
    const float* Wc = (const float*)d_in[9];
    const float* bc = (const float*)d_in[10];
    float* out = (float*)d_out;
    float* ws  = (float*)d_ws;

    prep<<<32, 256, 0, stream>>>(ew, ni, ws, out);
    gemm_h2<<<NT / 128, 256, 0, stream>>>(x, ni, W1, ws + WS_H2);
    deg_csr<<<BATCH_C, 256, 0, stream>>>(ei, ws);
    spmm<<<BATCH_C * 8, 256, 0, stream>>>(ws, ws + WS_H2, b1);
    reduce_g<<<256, 256, 0, stream>>>(ws + WS_H2, Wn, ws + WS_PART);
    final_out<<<8, 256, 0, stream>>>(ws, bn, Wc, bc, out);
}

// Round 4
// 258.893 us; speedup vs baseline: 2.2067x; 1.1329x over previous
//
#include <hip/hip_runtime.h>

#define N_NODES_C 1000
#define N_EDGES_C 8000
#define BATCH_C   64
#define IN_DIM_C  64
#define HID_C     128
#define NT (BATCH_C * N_NODES_C)   // 64000 total nodes
#define ET (BATCH_C * N_EDGES_C)   // 512000 total edges

// workspace layout (float offsets)
#define WS_DEG    0                 // 64000 f: deg -> dinv (in place)
#define WS_EWS    64000             // 8000 f: sparsified edge weights
#define WS_CNT    72000             // 64000 i: dst counts
#define WS_CUR    136000            // 64000 i: scatter cursors
#define WS_ROWP   200000            // 64*1024 i: per-graph CSR row starts
#define WS_PEDGE  265536            // 512000 int2: (src_global, norm) CSR order
#define WS_PART   1289536           // 256*2048 f: reduce_g partials
#define WS_H2     1813824           // 8192000 f: h2 (gemm output)
#define WS_RH     10005824          // 8192000 f: relu_h (if ws_size permits)
// with RH: 18,197,824 f = 72.8 MB ; without: 40.0 MB

// ---------------------------------------------------------------- prep ----
// ew sparsify + ni clamp (outputs), deg := 1 (self loop), cnt := 0
__global__ __launch_bounds__(256) void prep(const float* __restrict__ ew_in,
                                            const float* __restrict__ ni,
                                            float* __restrict__ ws,
                                            float* __restrict__ out) {
    int i = blockIdx.x * 256 + threadIdx.x;       // grid covers 64000
    if (i < NT) {
        ws[WS_DEG + i] = 1.0f;
        ((int*)(ws + WS_CNT))[i] = 0;
    }
    if (i < N_EDGES_C) {
        float w = ew_in[i];
        float s = (w < 0.2f) ? 0.0f : fminf(w, 1.0f);
        ws[WS_EWS + i] = s;
        out[128 + i] = s;                         // output 1: ew
    }
    if (i < N_NODES_C) {
        float v = ni[i];
        out[128 + N_EDGES_C + i] = fminf(fmaxf(v, 0.0f), 1.0f);  // output 2
    }
}

// ----------------------------------------------- weighted degree + count --
__global__ __launch_bounds__(256) void deg_cnt(const int* __restrict__ ei,
                                               float* __restrict__ ws) {
    int e = blockIdx.x * 256 + threadIdx.x;       // < ET
    int d = ei[ET + e];
    int le = e % N_EDGES_C;
    atomicAdd(&ws[WS_DEG + d], ws[WS_EWS + le]);
    atomicAdd(&((int*)(ws + WS_CNT))[d], 1);
}

// --------------------------------- per-graph: dinv + scan(cnt) -> rowp ----
__global__ __launch_bounds__(256) void csr_scan(float* __restrict__ ws) {
    __shared__ int rs[N_NODES_C + 8];
    __shared__ int wtot[4];
    int g = blockIdx.x, tid = threadIdx.x;
    int lane = tid & 63, wid = tid >> 6;
    int gbase = g * N_NODES_C;
    const int* cnt = (const int*)(ws + WS_CNT) + gbase;

    // deg -> dinv (in place)
    for (int i = tid; i < N_NODES_C; i += 256)
        ws[WS_DEG + gbase + i] = rsqrtf(ws[WS_DEG + gbase + i]);

    // exclusive scan of cnt (4 per thread + shfl scan)
    int s0 = 0, s1 = 0, s2 = 0, s3 = 0, tsum = 0;
    if (tid < 250) {
        s0 = cnt[4 * tid]; s1 = cnt[4 * tid + 1];
        s2 = cnt[4 * tid + 2]; s3 = cnt[4 * tid + 3];
        tsum = s0 + s1 + s2 + s3;
    }
    int v = tsum;
    #pragma unroll
    for (int off = 1; off < 64; off <<= 1) {
        int n = __shfl_up(v, off, 64);
        if (lane >= off) v += n;
    }
    if (lane == 63) wtot[wid] = v;
    __syncthreads();
    int base = 0;
    for (int w = 0; w < wid; ++w) base += wtot[w];
    int excl = base + v - tsum;
    if (tid < 250) {
        rs[4 * tid]     = excl;
        rs[4 * tid + 1] = excl + s0;
        rs[4 * tid + 2] = excl + s0 + s1;
        rs[4 * tid + 3] = excl + s0 + s1 + s2;
    }
    if (tid == 255) rs[N_NODES_C] = N_EDGES_C;
    __syncthreads();

    int* rowp = (int*)(ws + WS_ROWP) + g * 1024;
    int* cur  = (int*)(ws + WS_CUR) + gbase;
    for (int i = tid; i <= N_NODES_C; i += 256) rowp[i] = rs[i];
    for (int i = tid; i < N_NODES_C; i += 256) cur[i] = rs[i];
}

// ------------------------------------- scatter (src, norm) into CSR order -
__global__ __launch_bounds__(256) void scatter(const int* __restrict__ ei,
                                               float* __restrict__ ws) {
    int e = blockIdx.x * 256 + threadIdx.x;       // < ET
    int g = e / N_EDGES_C;
    int le = e - g * N_EDGES_C;
    int s = ei[e];
    int d = ei[ET + e];
    const float* dinv = ws + WS_DEG;
    float nm = dinv[s] * ws[WS_EWS + le] * dinv[d];
    int pos = atomicAdd(&((int*)(ws + WS_CUR))[d], 1);
    ((int2*)(ws + WS_PEDGE))[g * N_EDGES_C + pos] =
        make_int2(s, __float_as_int(nm));
}

// ------------------------------------------------------- h2 = (x*ni) @ W1 -
__global__ __launch_bounds__(256) void gemm_h2(const float* __restrict__ x,
                                               const float* __restrict__ ni,
                                               const float* __restrict__ W1,
                                               float* __restrict__ h2) {
    __shared__ float xs[128][65];
    __shared__ float wsm[64 * 128];
    int tid = threadIdx.x;
    int base = blockIdx.x * 128;

    #pragma unroll
    for (int i = 0; i < 8; ++i) {
        int idx = i * 1024 + tid * 4;
        int r = idx >> 6, d = idx & 63;
        float4 v = *(const float4*)&x[(base + r) * 64 + d];
        float s = ni[(base + r) % N_NODES_C];
        xs[r][d + 0] = v.x * s;
        xs[r][d + 1] = v.y * s;
        xs[r][d + 2] = v.z * s;
        xs[r][d + 3] = v.w * s;
    }
    #pragma unroll
    for (int i = 0; i < 8; ++i) {
        int idx = i * 1024 + tid * 4;
        *(float4*)&wsm[idx] = *(const float4*)&W1[idx];
    }
    __syncthreads();

    int tx = tid & 15, ty = tid >> 4;
    int r0 = ty * 8, c0 = tx * 8;
    float acc[8][8];
    #pragma unroll
    for (int i = 0; i < 8; ++i)
        #pragma unroll
        for (int j = 0; j < 8; ++j) acc[i][j] = 0.0f;

    for (int d = 0; d < 64; ++d) {
        float a[8];
        #pragma unroll
        for (int i = 0; i < 8; ++i) a[i] = xs[r0 + i][d];
        float4 b0 = *(float4*)&wsm[d * 128 + c0];
        float4 b1 = *(float4*)&wsm[d * 128 + c0 + 4];
        float b[8] = {b0.x, b0.y, b0.z, b0.w, b1.x, b1.y, b1.z, b1.w};
        #pragma unroll
        for (int i = 0; i < 8; ++i)
            #pragma unroll
            for (int j = 0; j < 8; ++j)
                acc[i][j] = fmaf(a[i], b[j], acc[i][j]);
    }

    #pragma unroll
    for (int i = 0; i < 8; ++i) {
        float* dst = &h2[(base + r0 + i) * HID_C + c0];
        float4 o0 = {acc[i][0], acc[i][1], acc[i][2], acc[i][3]};
        float4 o1 = {acc[i][4], acc[i][5], acc[i][6], acc[i][7]};
        *(float4*)dst = o0;
        *(float4*)(dst + 4) = o1;
    }
}

// ------------------------------------------- SpMM out-of-place (primary) --
// 2048 blocks: bid = slice*64 + g => bid%8 == g%8 (same XCD per graph;
// 512KB h2 slice L2-resident). Thread = one (dst, 16-feat chunk): register
// accumulation over CSR row, 4 independent float4 gathers per edge, NO LDS,
// no barrier -> ~32 waves/CU. Self-loop + bias + relu fused; writes rh.
__global__ __launch_bounds__(256) void spmm_op(const float* __restrict__ ws_ro,
                                               const float* __restrict__ h2,
                                               const float* __restrict__ b1,
                                               float* __restrict__ rh) {
    int bid = blockIdx.x;
    int g = bid & 63, slice = bid >> 6;            // slice < 32
    int t = threadIdx.x;
    if (t >= 250) return;
    int p = slice * 250 + t;                       // < 8000
    int dst = p >> 3, chunk = p & 7, c0 = chunk << 4;

    const int*  rowp  = (const int*)(ws_ro + WS_ROWP) + g * 1024;
    const int2* pedge = (const int2*)(ws_ro + WS_PEDGE) + g * N_EDGES_C;
    const float* dinv = ws_ro + WS_DEG;

    int e0 = rowp[dst], e1 = rowp[dst + 1];
    float4 a0 = {0,0,0,0}, a1 = {0,0,0,0}, a2 = {0,0,0,0}, a3 = {0,0,0,0};
    for (int e = e0; e < e1; ++e) {
        int2 ed = pedge[e];
        float nm = __int_as_float(ed.y);
        const float* hp = &h2[ed.x * HID_C + c0];
        float4 h0 = *(const float4*)(hp + 0);
        float4 h1 = *(const float4*)(hp + 4);
        float4 h2v = *(const float4*)(hp + 8);
        float4 h3 = *(const float4*)(hp + 12);
        a0.x = fmaf(h0.x, nm, a0.x); a0.y = fmaf(h0.y, nm, a0.y);
        a0.z = fmaf(h0.z, nm, a0.z); a0.w = fmaf(h0.w, nm, a0.w);
        a1.x = fmaf(h1.x, nm, a1.x); a1.y = fmaf(h1.y, nm, a1.y);
        a1.z = fmaf(h1.z, nm, a1.z); a1.w = fmaf(h1.w, nm, a1.w);
        a2.x = fmaf(h2v.x, nm, a2.x); a2.y = fmaf(h2v.y, nm, a2.y);
        a2.z = fmaf(h2v.z, nm, a2.z); a2.w = fmaf(h2v.w, nm, a2.w);
        a3.x = fmaf(h3.x, nm, a3.x); a3.y = fmaf(h3.y, nm, a3.y);
        a3.z = fmaf(h3.z, nm, a3.z); a3.w = fmaf(h3.w, nm, a3.w);
    }

    int node = g * N_NODES_C + dst;
    float dv = dinv[node], dv2 = dv * dv;
    const float* sp = &h2[node * HID_C + c0];
    float* op = &rh[node * HID_C + c0];
    #pragma unroll
    for (int q = 0; q < 4; ++q) {
        float4 sv = *(const float4*)(sp + q * 4);
        float4 bv = *(const float4*)&b1[c0 + q * 4];
        float4 av = q == 0 ? a0 : q == 1 ? a1 : q == 2 ? a2 : a3;
        float4 o;
        o.x = fmaxf(fmaf(sv.x, dv2, av.x) + bv.x, 0.0f);
        o.y = fmaxf(fmaf(sv.y, dv2, av.y) + bv.y, 0.0f);
        o.z = fmaxf(fmaf(sv.z, dv2, av.z) + bv.z, 0.0f);
        o.w = fmaxf(fmaf(sv.w, dv2, av.w) + bv.w, 0.0f);
        *(float4*)(op + q * 4) = o;
    }
}

// ------------------------- SpMM in-place fallback (small ws): 1024 thr ----
__global__ __launch_bounds__(1024) void spmm_ip(const float* __restrict__ ws_ro,
                                                float* __restrict__ h2,
                                                const float* __restrict__ b1) {
    __shared__ float res[N_NODES_C * 16];          // 64000 B
    int bid = blockIdx.x;
    int g  = bid & 63;
    int c0 = (bid >> 6) * 16;
    int tid = threadIdx.x;
    int fq = tid & 3, dslot = tid >> 2;            // 256 dsts in flight

    const int*  rowp  = (const int*)(ws_ro + WS_ROWP) + g * 1024;
    const int2* pedge = (const int2*)(ws_ro + WS_PEDGE) + g * N_EDGES_C;
    const float* dinv = ws_ro + WS_DEG;
    int gbase = g * N_NODES_C;

    for (int iter = 0; iter < 4; ++iter) {
        int d = iter * 256 + dslot;
        if (d < N_NODES_C) {
            int e0 = rowp[d], e1 = rowp[d + 1];
            float4 a = make_float4(0.f, 0.f, 0.f, 0.f);
            for (int e = e0; e < e1; ++e) {
                int2 ed = pedge[e];
                float nm = __int_as_float(ed.y);
                float4 hv = *(const float4*)&h2[ed.x * HID_C + c0 + fq * 4];
                a.x = fmaf(hv.x, nm, a.x);
                a.y = fmaf(hv.y, nm, a.y);
                a.z = fmaf(hv.z, nm, a.z);
                a.w = fmaf(hv.w, nm, a.w);
            }
            *(float4*)&res[d * 16 + fq * 4] = a;
        }
    }
    __syncthreads();

    for (int idx = tid; idx < N_NODES_C * 16; idx += 1024) {
        int v = idx >> 4, f = idx & 15;
        int node = gbase + v;
        float dv = dinv[node];
        float val = res[idx] + h2[node * HID_C + c0 + f] * (dv * dv) + b1[c0 + f];
        h2[node * HID_C + c0 + f] = fmaxf(val, 0.0f);
    }
}

// ------------------------------------------- g partials: rh @ Wn chunks ---
__global__ __launch_bounds__(256) void reduce_g(const float* __restrict__ rh,
                                                const float* __restrict__ Wn,
                                                float* __restrict__ part) {
    int tid = threadIdx.x;
    int j = tid & 31, bg = tid >> 5;
    int k0 = blockIdx.x * 500;
    float acc[8] = {0, 0, 0, 0, 0, 0, 0, 0};
    for (int kk = 0; kk < 500; kk += 4) {
        int k = k0 + kk;
        float w0 = Wn[(k + 0) * 32 + j];
        float w1 = Wn[(k + 1) * 32 + j];
        float w2 = Wn[(k + 2) * 32 + j];
        float w3 = Wn[(k + 3) * 32 + j];
        #pragma unroll
        for (int u = 0; u < 8; ++u) {
            float4 r = *(const float4*)&rh[(bg * 8 + u) * 128000 + k];
            acc[u] = fmaf(r.x, w0, acc[u]);
            acc[u] = fmaf(r.y, w1, acc[u]);
            acc[u] = fmaf(r.z, w2, acc[u]);
            acc[u] = fmaf(r.w, w3, acc[u]);
        }
    }
    #pragma unroll
    for (int u = 0; u < 8; ++u)
        part[blockIdx.x * 2048 + (bg * 8 + u) * 32 + j] = acc[u];
}

// ---------------------- final: sum partials, +bn, @Wc, +bc (shfl reduce) --
__global__ __launch_bounds__(256) void final_out(const float* __restrict__ ws_ro,
                                                 const float* __restrict__ bn,
                                                 const float* __restrict__ Wc,
                                                 const float* __restrict__ bc,
                                                 float* __restrict__ out) {
    int gid = blockIdx.x * 256 + threadIdx.x;      // 2048 = 64 graphs x 32 j
    int g = gid >> 5, j = gid & 31;
    const float* part = ws_ro + WS_PART;
    float s = 0.0f;
    for (int c = 0; c < 256; ++c)
        s += part[c * 2048 + gid];
    float gv = s + bn[j];
    float o0 = gv * Wc[j * 2 + 0];
    float o1 = gv * Wc[j * 2 + 1];
    #pragma unroll
    for (int off = 16; off >= 1; off >>= 1) {
        o0 += __shfl_xor(o0, off);
        o1 += __shfl_xor(o1, off);
    }
    if (j == 0) {
        out[g * 2 + 0] = o0 + bc[0];
        out[g * 2 + 1] = o1 + bc[1];
    }
}

// --------------------------------------------------------------------------
extern "C" void kernel_launch(void* const* d_in, const int* in_sizes, int n_in,
                              void* d_out, int out_size, void* d_ws, size_t ws_size,
                              hipStream_t stream) {
    const float* x  = (const float*)d_in[0];
    const int*   ei = (const int*)d_in[1];
    const float* ew = (const float*)d_in[3];
    const float* ni = (const float*)d_in[4];
    const float* W1 = (const float*)d_in[5];
    const float* b1 = (const float*)d_in[6];
    const float* Wn = (const float*)d_in[7];
    const float* bn = (const float*)d_in[8];
    const float* Wc = (const float*)d_in[9];
    const float* bc = (const float*)d_in[10];
    float* out = (float*)d_out;
    float* ws  = (float*)d_ws;

    bool big = ws_size >= (size_t)(WS_RH + 8192000) * sizeof(float);
    float* h2 = ws + WS_H2;
    float* rh = big ? ws + WS_RH : h2;

    prep<<<NT / 256, 256, 0, stream>>>(ew, ni, ws, out);
    gemm_h2<<<NT / 128, 256, 0, stream>>>(x, ni, W1, h2);
    deg_cnt<<<ET / 256, 256, 0, stream>>>(ei, ws);
    csr_scan<<<BATCH_C, 256, 0, stream>>>(ws);
    scatter<<<ET / 256, 256, 0, stream>>>(ei, ws);
    if (big)
        spmm_op<<<BATCH_C * 32, 256, 0, stream>>>(ws, h2, b1, rh);
    else
        spmm_ip<<<BATCH_C * 8, 1024, 0, stream>>>(ws, h2, b1);
    reduce_g<<<256, 256, 0, stream>>>(rh, Wn, ws + WS_PART);
    final_out<<<8, 256, 0, stream>>>(ws, bn, Wc, bc, out);
}